// Round 19
// baseline (517.070 us; speedup 1.0000x reference)
//
#include <hip/hip_runtime.h>
#include <hip/hip_bf16.h>
#include <math.h>

typedef __hip_bfloat16 bf16;
typedef unsigned short ushort;
typedef __attribute__((ext_vector_type(8))) short short8;
typedef __attribute__((ext_vector_type(4))) float float4v;

#define BATCH 64
#define NPIX 596
#define CH 34
#define PC 256

static __device__ __forceinline__ ushort f2bu(float v){ bf16 h = __float2bfloat16(v); return *(ushort*)&h; }
static __device__ __forceinline__ float bu2f(ushort u){ bf16 h = *(bf16*)&u; return __bfloat162float(h); }
static __device__ __forceinline__ float eluf(float x){ return x > 0.f ? x : expm1f(x); }

// ---------------------------------------------------------------------------
// K_front: fusion of conv(512 blocks) + weight-prep(262 blocks) + zeroing.
// Conv path stages feats H/L in LDS and emits coalesced short8 rows.
// ---------------------------------------------------------------------------
__global__ __launch_bounds__(256) void k_front(
    const float* __restrict__ x,
    const float* __restrict__ w1, const float* __restrict__ b1,
    const float* __restrict__ w2, const float* __restrict__ b2,
    const float* __restrict__ aw, const float* __restrict__ qw, const float* __restrict__ kw,
    const float* __restrict__ l1w,
    const float* __restrict__ kpw, const float* __restrict__ qpw, const float* __restrict__ vpw,
    ushort* __restrict__ featsH, ushort* __restrict__ featsL,
    ushort* __restrict__ alinP, ushort* __restrict__ WqkP, ushort* __restrict__ w1T,
    ushort* __restrict__ projP,
    float* __restrict__ zbuf)
{
  __shared__ float shm_[8752];
  const int t = threadIdx.x;
  const int id = blockIdx.x;

  if (id < 512){
    float* sw1 = shm_;          // 256
    float* sb1 = shm_ + 256;    // 16
    float* sw2 = shm_ + 272;    // 2048
    float* sb2 = shm_ + 2320;   // 32
    float* h1  = shm_ + 2352;   // 1600 (ends 3952)
    ushort* fHt = (ushort*)(shm_ + 3952);   // 75*64 = 4800 ushorts
    ushort* fLt = fHt + 4800;               // 4800 ushorts
    const int s = id & 7, b = id >> 3;
    const float* xb = x + (size_t)b * 4*151*6;

    const int p0 = s*75;
    const int p1 = (p0+75 < NPIX) ? p0+75 : NPIX;
    const int rA = p0>>2, rB = (p1-1)>>2;
    const int nh = rB - rA + 2;

    sw1[t]=w1[t];
    if (t<16) sb1[t]=b1[t];
    for (int i=t;i<2048;i+=256) sw2[i]=w2[i];
    if (t<32) sb2[t]=b2[t];
    __syncthreads();

    for (int i=t; i<16*nh*5; i+=256){
      int oc = i/(nh*5), rem = i - oc*(nh*5);
      int lr = rem/5, cc = rem - (rem/5)*5;
      int r = rA + lr;
      float acc = sb1[oc];
      #pragma unroll
      for (int ic=0;ic<4;ic++){
        const float* xp = xb + ic*906 + r*6 + cc;
        const float* wp = sw1 + oc*16 + ic*4;
        acc += xp[0]*wp[0] + xp[1]*wp[1] + xp[6]*wp[2] + xp[7]*wp[3];
      }
      h1[(oc*20 + lr)*5 + cc] = fmaxf(acc, 0.f);
    }
    __syncthreads();

    const int np = p1 - p0;
    const short8 z8 = {0,0,0,0,0,0,0,0};
    for (int i=t;i<np*3;i+=256){
      int pl = i/3, off = 40 + (i - pl*3)*8;
      *(short8*)(fHt + pl*64 + off) = z8;
      *(short8*)(fLt + pl*64 + off) = z8;
    }
    for (int i=t;i<32*np;i+=256){
      int oc = i/np, pl = i - oc*np;
      int p = p0 + pl;
      int r = p>>2, cc = p&3;
      int lr = r - rA;
      float acc = sb2[oc];
      #pragma unroll
      for (int ic=0;ic<16;ic++){
        const float* hp = h1 + (ic*20 + lr)*5 + cc;
        const float* wp = sw2 + oc*64 + ic*4;
        acc += hp[0]*wp[0] + hp[1]*wp[1] + hp[5]*wp[2] + hp[6]*wp[3];
      }
      float v = fmaxf(acc, 0.f);
      ushort hu = f2bu(v);
      fHt[pl*64+oc] = hu;
      fLt[pl*64+oc] = f2bu(v - bu2f(hu));
    }
    for (int pl=t; pl<np; pl+=256){
      int p = p0 + pl;
      float v1 = (float)(p&3)*0.25f;
      float v2 = (float)(p>>2)*(1.0f/149.0f);
      ushort h1u = f2bu(v1), h2u = f2bu(v2);
      fHt[pl*64+32] = h1u;  fLt[pl*64+32] = f2bu(v1 - bu2f(h1u));
      fHt[pl*64+33] = h2u;  fLt[pl*64+33] = f2bu(v2 - bu2f(h2u));
      #pragma unroll
      for (int e=34;e<40;e++){ fHt[pl*64+e] = 0; fLt[pl*64+e] = 0; }
    }
    __syncthreads();
    ushort* fbH = featsH + (size_t)b*NPIX*64;
    ushort* fbL = featsL + (size_t)b*NPIX*64;
    for (int sid=t; sid<np*8; sid+=256){
      int row = sid>>3, c8 = (sid&7)*8;
      int p = p0 + row;
      *(short8*)(fbH + (size_t)p*64 + c8) = *(short8*)(fHt + row*64 + c8);
      *(short8*)(fbL + (size_t)p*64 + c8) = *(short8*)(fLt + row*64 + c8);
    }
  } else if (id < 774){
    const int w = t>>6, l = t&63;
    const int gw = (id - 512)*4 + w;
    #define SA(W_,R_,C_) shm_[(W_)*544 + (R_)*17 + (C_)]
    if (gw < 1016){
      const float* src; ushort* dst;
      int row0, col0, nrow, ncol, rstride; size_t slot;
      if (gw < 760){
        int tile = gw/19, kk = gw - tile*19;
        src = aw; rstride = NPIX; nrow = NPIX; ncol = NPIX;
        row0 = kk*32; col0 = tile*16;
        dst = alinP; slot = (size_t)gw*64;
      } else if (gw < 920){
        int g1 = gw - 760;
        int tile = g1>>2, kk = g1&3;
        rstride = NPIX; nrow = 64; ncol = NPIX;
        col0 = tile*16;
        if (kk < 2){ src = qw; row0 = kk*32; }
        else       { src = kw; row0 = (kk-2)*32; }
        dst = WqkP; slot = (size_t)g1*64;
      } else {
        int g2 = gw - 920;
        int which = g2>>5, rem = g2&31;
        int tile = rem>>1, kk = rem&1;
        src = which==0 ? kpw : which==1 ? qpw : vpw;
        rstride = PC; nrow = CH; ncol = PC;
        row0 = kk*32; col0 = tile*16;
        dst = projP; slot = (size_t)g2*64;
      }
      #pragma unroll
      for (int p=0;p<2;p++){
        int rr = p*16 + (l>>2);
        int r = row0 + rr;
        int cb = (l&3)*4;
        #pragma unroll
        for (int j=0;j<4;j++){
          int c = col0 + cb + j;
          float v = (r < nrow && c < ncol) ? src[(size_t)r*rstride + c] : 0.f;
          SA(w, rr, cb+j) = v;
        }
      }
      __syncthreads();
      int nloc = l&15, c0 = (l>>4)*8;
      ushort out[8];
      #pragma unroll
      for (int i=0;i<8;i++) out[i] = f2bu(SA(w, c0+i, nloc));
      *(short8*)(dst + (slot + l)*8) = *(short8*)out;
    } else {
      int s3 = (gw - 1016)*64 + l;      // 0..2047
      int n = s3>>5, e0 = (s3&31)*8;
      ushort out[8];
      #pragma unroll
      for (int i=0;i<8;i++) out[i] = f2bu(l1w[(size_t)(e0+i)*64 + n]);
      *(short8*)(w1T + (size_t)s3*8) = *(short8*)out;
    }
    #undef SA
  } else {
    for (int i=t;i<4624;i+=256) zbuf[i] = 0.f;
  }
}

// ---------------------------------------------------------------------------
// P1 (MFMA): proj stats. grid (5 rb-pairs, 64 b, 3 which).
// ---------------------------------------------------------------------------
__global__ __launch_bounds__(256) void k_proj_p1(
    const ushort* __restrict__ featsH, const ushort* __restrict__ featsL,
    const ushort* __restrict__ projP,
    const float* __restrict__ kpb, const float* __restrict__ qpb, const float* __restrict__ vpb,
    float* __restrict__ statsP)
{
  __shared__ float red[8];
  const int b = blockIdx.y, which = blockIdx.z;
  const int t = threadIdx.x, w = t>>6, l = t&63, quad = l>>4, ln = l&15;
  const float* Bv = which==0 ? kpb : which==1 ? qpb : vpb;

  float s=0.f, s2=0.f;
  for (int rr=0; rr<2; rr++){
    const int rb = blockIdx.x*2 + rr;
    float4v acc[4][4];
    #pragma unroll
    for (int ms=0;ms<4;ms++)
      #pragma unroll
      for (int i=0;i<4;i++) acc[ms][i] = (float4v){0.f,0.f,0.f,0.f};

    #pragma unroll
    for (int kk=0;kk<4;kk++){
      const ushort* fb = (kk<2 ? featsH : featsL) + (size_t)b*NPIX*64;
      short8 aq[4];
      #pragma unroll
      for (int ms=0;ms<4;ms++){
        int r = rb*64 + ms*16 + ln;
        short8 z = {0,0,0,0,0,0,0,0};
        aq[ms] = (r < NPIX) ? *(const short8*)(fb + (size_t)r*64 + (kk&1)*32 + quad*8) : z;
      }
      #pragma unroll
      for (int i=0;i<4;i++){
        int tile = w + 4*i;
        short8 bf = *(const short8*)(projP + ((size_t)((which*16 + tile)*2 + (kk&1))*64 + l)*8);
        #pragma unroll
        for (int ms=0;ms<4;ms++)
          acc[ms][i] = __builtin_amdgcn_mfma_f32_16x16x32_bf16(aq[ms], bf, acc[ms][i], 0,0,0);
      }
    }
    #pragma unroll
    for (int i=0;i<4;i++){
      int col = (w+4*i)*16 + ln;
      float bc = Bv[col];
      #pragma unroll
      for (int ms=0;ms<4;ms++)
        #pragma unroll
        for (int r=0;r<4;r++){
          int p = rb*64 + ms*16 + quad*4 + r;
          if (p < NPIX){
            float v = acc[ms][i][r] + bc;
            s += v; s2 += v*v;
          }
        }
    }
  }
  #pragma unroll
  for (int o=32;o>0;o>>=1){ s += __shfl_down(s,o); s2 += __shfl_down(s2,o); }
  if (l==0){ red[w]=s; red[4+w]=s2; }
  __syncthreads();
  if (t==0){
    atomicAdd(&statsP[(which*64+b)*2],   red[0]+red[1]+red[2]+red[3]);
    atomicAdd(&statsP[(which*64+b)*2+1], red[4]+red[5]+red[6]+red[7]);
  }
}

// ---------------------------------------------------------------------------
// P2 (MFMA): proj recompute + LN + affine; coalesced short8 emission.
// grid (5 rb-pairs, 64 b, 3 which) -- 2 row-blocks per block, vtile reused.
// ---------------------------------------------------------------------------
__global__ __launch_bounds__(256) void k_proj_p2(
    const ushort* __restrict__ featsH, const ushort* __restrict__ featsL,
    const ushort* __restrict__ projP,
    const float* __restrict__ kpb, const float* __restrict__ qpb, const float* __restrict__ vpb,
    const float* __restrict__ kg, const float* __restrict__ kb_,
    const float* __restrict__ qg, const float* __restrict__ qb_,
    const float* __restrict__ vg, const float* __restrict__ vb_,
    const float* __restrict__ statsP,
    ushort* __restrict__ Kb, ushort* __restrict__ Qb, ushort* __restrict__ VP)
{
  __shared__ ushort vtile[64*264];
  const int b = blockIdx.y, which = blockIdx.z;
  const int t = threadIdx.x, w = t>>6, l = t&63, quad = l>>4, ln = l&15;
  const float* Bv = which==0 ? kpb : which==1 ? qpb : vpb;
  const float* G  = which==0 ? kg  : which==1 ? qg  : vg;
  const float* Be = which==0 ? kb_ : which==1 ? qb_ : vb_;

  const float n = (float)(NPIX*PC);
  const float S  = statsP[(which*64+b)*2];
  const float S2 = statsP[(which*64+b)*2+1];
  const float mu = S/n;
  const float rs = rsqrtf(S2/n - mu*mu + 1e-5f);

  for (int rr=0; rr<2; rr++){
    const int rb = blockIdx.x*2 + rr;
    float4v acc[4][4];
    #pragma unroll
    for (int ms=0;ms<4;ms++)
      #pragma unroll
      for (int i=0;i<4;i++) acc[ms][i] = (float4v){0.f,0.f,0.f,0.f};

    #pragma unroll
    for (int kk=0;kk<4;kk++){
      const ushort* fb = (kk<2 ? featsH : featsL) + (size_t)b*NPIX*64;
      short8 aq[4];
      #pragma unroll
      for (int ms=0;ms<4;ms++){
        int r = rb*64 + ms*16 + ln;
        short8 z = {0,0,0,0,0,0,0,0};
        aq[ms] = (r < NPIX) ? *(const short8*)(fb + (size_t)r*64 + (kk&1)*32 + quad*8) : z;
      }
      #pragma unroll
      for (int i=0;i<4;i++){
        int tile = w + 4*i;
        short8 bf = *(const short8*)(projP + ((size_t)((which*16 + tile)*2 + (kk&1))*64 + l)*8);
        #pragma unroll
        for (int ms=0;ms<4;ms++)
          acc[ms][i] = __builtin_amdgcn_mfma_f32_16x16x32_bf16(aq[ms], bf, acc[ms][i], 0,0,0);
      }
    }

    if (rr) __syncthreads();   // prior emission reads done before overwrite
    #pragma unroll
    for (int i=0;i<4;i++){
      int col = (w+4*i)*16 + ln;
      int h = col>>6, d = col&63;
      float bc = Bv[col];
      #pragma unroll
      for (int ms=0;ms<4;ms++)
        #pragma unroll
        for (int r=0;r<4;r++){
          int lrow = ms*16 + quad*4 + r;
          int p = rb*64 + lrow;
          ushort o = 0;
          if (p < NPIX){
            int gi = (h*NPIX+p)*64 + d;
            o = f2bu((acc[ms][i][r] + bc - mu)*rs*G[gi] + Be[gi]);
          }
          vtile[lrow*264 + col] = o;
        }
    }
    __syncthreads();

    if (which < 2){
      ushort* out = which==0 ? Kb : Qb;
      #pragma unroll
      for (int e=0;e<8;e++){
        int sid = e*256 + t;              // 0..2047
        int row = sid>>5, c8 = (sid&31)*8;
        int p = rb*64 + row;
        if (p < NPIX){
          int h = c8>>6, d0 = c8&63;
          *(short8*)(out + ((size_t)(b*4+h)*NPIX + p)*64 + d0) = *(short8*)(vtile + row*264 + c8);
        }
      }
    } else {
      #pragma unroll
      for (int e=0;e<8;e++){
        int sid = e*256 + t;              // 0..2047
        int l2 = sid & 63;
        int rest = sid >> 6;              // ((hh*4+w2)*2+kkL)
        int kkL = rest & 1, w2 = (rest>>1)&3, hh = rest>>3;
        int kk = rb*2 + kkL;
        if (kk < 19){
          int lrow0 = kkL*32 + ((l2>>4)<<3);
          int col = hh*64 + w2*16 + (l2&15);
          ushort o[8];
          #pragma unroll
          for (int jj=0;jj<8;jj++) o[jj] = vtile[(lrow0+jj)*264 + col];
          *(short8*)(VP + ((size_t)(b*4+hh)*4864 + (w2*19 + kk)*64 + l2)*8) = *(short8*)o;
        }
      }
    }
  }
}

// ---------------------------------------------------------------------------
// K3: fused MFMA attention (unchanged from R17: 263us best).
// ---------------------------------------------------------------------------
__global__ __launch_bounds__(512, 1) void k_attn(
    const ushort* __restrict__ Qb, const ushort* __restrict__ Kb,
    const ushort* __restrict__ alinP, const ushort* __restrict__ WqkP,
    const ushort* __restrict__ VP,
    const float* __restrict__ qbias, const float* __restrict__ kbias,
    const float* __restrict__ abias,
    ushort* __restrict__ Ew)
{
  extern __shared__ __align__(16) ushort sm[];
  ushort* strip = sm;                         // 128*616 = 78,848 halves
  float*  red   = (float*)(sm + 78848);       // 1024 f32
  float*  rsum  = (float*)(sm + 78848 + 2048);// 128 f32

  const int t = threadIdx.x;
  const int w = t>>6, l = t&63, quad = l>>4, ln = l&15;
  const int id  = blockIdx.x + blockIdx.y*5;     // 0..1279
  const int xcd = id & 7, idx = id >> 3;         // idx 0..159
  const int lin = xcd*160 + idx;
  const int bh  = lin/5, rb = lin - bh*5;
  const int b = bh>>2, h = bh&3;
  const int row0 = rb*128;
  const ushort* Qp = Qb + (size_t)bh*NPIX*64;
  const ushort* Kp = Kb + (size_t)bh*NPIX*64;

  float4v acc[8][5];
  #pragma unroll
  for (int ms=0;ms<8;ms++)
    #pragma unroll
    for (int i=0;i<5;i++) acc[ms][i] = (float4v){0.f,0.f,0.f,0.f};

  // ---------------- A0 = elu([Q|K] @ Wqk + qb + kb) ----------------
  #pragma unroll
  for (int kk=0;kk<4;kk++){
    short8 aq[8];
    #pragma unroll
    for (int ms=0;ms<8;ms++){
      int r = row0 + ms*16 + ln;
      short8 z = {0,0,0,0,0,0,0,0};
      aq[ms] = (r < NPIX)
        ? *(const short8*)((kk<2 ? Qp : Kp) + (size_t)r*64 + (kk&1)*32 + quad*8) : z;
    }
    __builtin_amdgcn_s_setprio(1);
    #pragma unroll
    for (int i=0;i<5;i++){
      int tile = w + 8*i;
      short8 bf = *(const short8*)(WqkP + ((size_t)(tile*4 + kk)*64 + l)*8);
      #pragma unroll
      for (int ms=0;ms<8;ms++)
        acc[ms][i] = __builtin_amdgcn_mfma_f32_16x16x32_bf16(aq[ms], bf, acc[ms][i], 0,0,0);
    }
    __builtin_amdgcn_s_setprio(0);
  }
  // epilogue: bias + elu -> strip
  #pragma unroll
  for (int i=0;i<5;i++){
    int t0 = w + 8*i;
    if (t0 < 38){
      int col = t0*16 + ln;
      bool cv = col < NPIX;
      float qkb = cv ? (qbias[col] + kbias[col]) : 0.f;
      #pragma unroll
      for (int ms=0;ms<8;ms++)
        #pragma unroll
        for (int r=0;r<4;r++){
          float v = 0.f;
          if (cv){ float xx = acc[ms][i][r] + qkb; v = xx > 0.f ? xx : __expf(xx) - 1.f; }
          strip[(ms*16+quad*4+r)*616 + col] = f2bu(v);
        }
    }
  }
  __syncthreads();

  // ---------------- S = A0 @ alin (2-stage B prefetch) ----------------
  #pragma unroll
  for (int ms=0;ms<8;ms++)
    #pragma unroll
    for (int i=0;i<5;i++) acc[ms][i] = (float4v){0.f,0.f,0.f,0.f};

#define LDB(dst, KK) \
  { _Pragma("unroll") \
    for (int i=0;i<5;i++) \
      dst[i] = *(const short8*)(alinP + ((size_t)((w+8*i)*19 + (KK))*64 + l)*8); }
#define SCOMP(KK, bfv) \
  { short8 af[8]; \
    _Pragma("unroll") \
    for (int ms=0;ms<8;ms++) \
      af[ms] = *(const short8*)(strip + (ms*16+ln)*616 + (KK)*32 + quad*8); \
    __builtin_amdgcn_s_setprio(1); \
    _Pragma("unroll") \
    for (int i=0;i<5;i++){ \
      _Pragma("unroll") \
      for (int ms=0;ms<8;ms++) \
        acc[ms][i] = __builtin_amdgcn_mfma_f32_16x16x32_bf16(af[ms], bfv[i], acc[ms][i], 0,0,0); \
    } \
    __builtin_amdgcn_s_setprio(0); }

  {
    short8 bfA[5], bfB[5];
    LDB(bfA, 0);
    for (int kk=0; kk<18; kk+=2){
      LDB(bfB, kk+1);
      SCOMP(kk, bfA);
      LDB(bfA, kk+2);
      SCOMP(kk+1, bfB);
    }
    SCOMP(18, bfA);
  }
  __syncthreads();   // all strip (A0) reads done before P overwrites it

  // -------- fused exp + row-sum, unnormalized P -> strip (no max pass) -----
  float sum[8][4];
  #pragma unroll
  for (int ms=0;ms<8;ms++)
    #pragma unroll
    for (int r=0;r<4;r++) sum[ms][r] = 0.f;
  #pragma unroll
  for (int i=0;i<5;i++){
    int t0 = w + 8*i;
    if (t0 < 38){
      int col = t0*16 + ln;
      bool cv = col < NPIX;
      float ab = cv ? abias[col] : 0.f;
      #pragma unroll
      for (int ms=0;ms<8;ms++)
        #pragma unroll
        for (int r=0;r<4;r++){
          float e = cv ? __expf(acc[ms][i][r] + ab) : 0.f;
          sum[ms][r] += e;
          strip[(ms*16+quad*4+r)*616 + col] = f2bu(e);
        }
    }
  }
  #pragma unroll
  for (int ms=0;ms<8;ms++)
    #pragma unroll
    for (int r=0;r<4;r++)
      #pragma unroll
      for (int o=8;o>0;o>>=1) sum[ms][r] += __shfl_xor(sum[ms][r], o, 16);
  if (ln==0){
    #pragma unroll
    for (int ms=0;ms<8;ms++)
      #pragma unroll
      for (int r=0;r<4;r++) red[(ms*16+quad*4+r)*8 + w] = sum[ms][r];
  }
  __syncthreads();
  if (t < 128){
    float4v v0 = *(float4v*)&red[t*8];
    float4v v1 = *(float4v*)&red[t*8+4];
    rsum[t] = (v0[0]+v0[1]+v0[2]+v0[3]) + (v1[0]+v1[1]+v1[2]+v1[3]);
  }
  __syncthreads();

  // ---------------- E = (P_unnorm @ V) * inv_rowsum (2-stage prefetch) ----
  const int wr = w>>2, wc = w&3;
  float4v ve[4];
  #pragma unroll
  for (int ms=0;ms<4;ms++) ve[ms] = (float4v){0.f,0.f,0.f,0.f};

#define LDV(dst, KK) \
  dst = *(const short8*)(VP + ((size_t)bh*4864 + (wc*19 + (KK))*64 + l)*8);
#define PVCOMP(KK, bfv) \
  { __builtin_amdgcn_s_setprio(1); \
    _Pragma("unroll") \
    for (int ms=0;ms<4;ms++){ \
      short8 af = *(const short8*)(strip + (wr*64 + ms*16+ln)*616 + (KK)*32 + quad*8); \
      ve[ms] = __builtin_amdgcn_mfma_f32_16x16x32_bf16(af, bfv, ve[ms], 0,0,0); \
    } \
    __builtin_amdgcn_s_setprio(0); }

  {
    short8 vA, vB;
    LDV(vA, 0);
    for (int kk=0; kk<18; kk+=2){
      LDV(vB, kk+1);
      PVCOMP(kk, vA);
      LDV(vA, kk+2);
      PVCOMP(kk+1, vB);
    }
    PVCOMP(18, vA);
  }

  // stage E in dead strip, then coalesced short8 Ew writes
  __syncthreads();   // all strip (P) reads done
  {
    ushort* esh = sm;  // 128 rows x 64 cols, stride 72
    #pragma unroll
    for (int ms=0;ms<4;ms++)
      #pragma unroll
      for (int r=0;r<4;r++){
        int lrow = wr*64 + ms*16 + quad*4 + r;
        esh[lrow*72 + wc*16 + ln] = f2bu(ve[ms][r] / rsum[lrow]);
      }
    __syncthreads();
    #pragma unroll
    for (int e=0;e<2;e++){
      int sid = e*512 + t;          // 0..1023 = 128 rows x 8 chunks
      int row = sid>>3, c8 = (sid&7)*8;
      int p = row0 + row;
      if (p < NPIX)
        *(short8*)(Ew + ((size_t)b*NPIX + p)*256 + h*64 + c8) = *(short8*)(esh + row*72 + c8);
    }
  }
}

// ---------------------------------------------------------------------------
// K4: lin1 via MFMA + relu + per-batch LN stats + per-column max; last-block
// tail does final LN+lin2+elu (device-scope atomics + threadfence).
// ---------------------------------------------------------------------------
__global__ __launch_bounds__(256) void k_lin1(
    const ushort* __restrict__ Ew, const ushort* __restrict__ w1T,
    const float* __restrict__ bias,
    float* __restrict__ colmax, float* __restrict__ stats,
    int* __restrict__ done,
    const float* __restrict__ w2, const float* __restrict__ b2v,
    float* __restrict__ out)
{
  __shared__ ushort sw1[64*264];
  __shared__ float red[8];
  __shared__ int lastFlag;
  const int t = threadIdx.x;
  const int w = t>>6, l = t&63, quad = l>>4, ln = l&15;
  const int rb = blockIdx.x, b = blockIdx.y;
  for (int g=t; g<2048; g+=256){
    int row = g>>5, q = g&31;
    *(short8*)(sw1 + row*264 + q*8) = *(const short8*)(w1T + row*256 + q*8);
  }
  __syncthreads();
  float4v acc[4];
  #pragma unroll
  for (int ms=0;ms<4;ms++) acc[ms] = (float4v){0.f,0.f,0.f,0.f};
  #pragma unroll
  for (int kk=0;kk<8;kk++){
    short8 bf = *(const short8*)(sw1 + (w*16+ln)*264 + kk*32 + quad*8);
    #pragma unroll
    for (int ms=0;ms<4;ms++){
      int p = rb*64 + ms*16 + ln;
      size_t rowi = (size_t)b*NPIX + (p < NPIX ? p : 0);
      short8 a = *(const short8*)(Ew + rowi*256 + kk*32 + quad*8);
      acc[ms] = __builtin_amdgcn_mfma_f32_16x16x32_bf16(a, bf, acc[ms], 0,0,0);
    }
  }
  const int col = w*16 + ln;
  const float bc = bias[col];
  float s=0.f, s2=0.f, cmx=0.f;
  #pragma unroll
  for (int ms=0;ms<4;ms++)
    #pragma unroll
    for (int r=0;r<4;r++){
      int p = rb*64 + ms*16 + quad*4 + r;
      if (p < NPIX){
        float v = fmaxf(acc[ms][r] + bc, 0.f);
        s += v; s2 += v*v;
        cmx = fmaxf(cmx, v);
      }
    }
  cmx = fmaxf(cmx, __shfl_xor(cmx, 16, 64));
  cmx = fmaxf(cmx, __shfl_xor(cmx, 32, 64));
  if (quad == 0)
    atomicMax((int*)&colmax[b*64 + col], __float_as_int(cmx));
  #pragma unroll
  for (int o=32;o>0;o>>=1){ s += __shfl_down(s,o); s2 += __shfl_down(s2,o); }
  if (l==0){ red[w]=s; red[4+w]=s2; }
  __syncthreads();
  if (t==0){
    atomicAdd(&stats[b*2],   red[0]+red[1]+red[2]+red[3]);
    atomicAdd(&stats[b*2+1], red[4]+red[5]+red[6]+red[7]);
    __threadfence();
    int v = atomicAdd(done, 1);
    lastFlag = (v == 639);
  }
  __syncthreads();
  if (lastFlag && t < 64){
    const int bb = t;
    const float n = (float)(NPIX*64);
    float S = stats[bb*2], S2 = stats[bb*2+1];
    float mu = S/n, var = S2/n - mu*mu;
    float rs = rsqrtf(var + 1e-5f);
    float accv[10];
    #pragma unroll
    for (int j=0;j<10;j++) accv[j] = b2v[j];
    for (int e=0;e<64;e++){
      float nm = (colmax[bb*64+e] - mu) * rs;
      #pragma unroll
      for (int j=0;j<10;j++) accv[j] += nm * w2[e*10+j];
    }
    #pragma unroll
    for (int j=0;j<10;j++) out[bb*10+j] = eluf(accv[j]);
  }
}

// ---------------------------------------------------------------------------
extern "C" void kernel_launch(void* const* d_in, const int* in_sizes, int n_in,
                              void* d_out, int out_size, void* d_ws, size_t ws_size,
                              hipStream_t stream)
{
  const float* x       = (const float*)d_in[0];
  const float* conv1_w = (const float*)d_in[1];
  const float* conv1_b = (const float*)d_in[2];
  const float* conv2_w = (const float*)d_in[3];
  const float* conv2_b = (const float*)d_in[4];
  const float* kp_w    = (const float*)d_in[5];
  const float* kp_b    = (const float*)d_in[6];
  const float* qp_w    = (const float*)d_in[7];
  const float* qp_b    = (const float*)d_in[8];
  const float* vp_w    = (const float*)d_in[9];
  const float* vp_b    = (const float*)d_in[10];
  const float* klin_w  = (const float*)d_in[11];
  const float* klin_b  = (const float*)d_in[12];
  const float* qlin_w  = (const float*)d_in[13];
  const float* qlin_b  = (const float*)d_in[14];
  const float* alin_w  = (const float*)d_in[15];
  const float* alin_b  = (const float*)d_in[16];
  const float* knorm_g = (const float*)d_in[17];
  const float* knorm_b = (const float*)d_in[18];
  const float* qnorm_g = (const float*)d_in[19];
  const float* qnorm_b = (const float*)d_in[20];
  const float* vnorm_g = (const float*)d_in[21];
  const float* vnorm_b = (const float*)d_in[22];
  const float* lin1_w  = (const float*)d_in[23];
  const float* lin1_b  = (const float*)d_in[24];
  const float* lin2_w  = (const float*)d_in[25];
  const float* lin2_b  = (const float*)d_in[26];

  // workspace layout
  float* feats  = (float*)d_ws;                         // holds featsH bf16
  float* F      = feats + (size_t)BATCH*NPIX*CH;        // holds featsL bf16
  float* statsE = F + (size_t)BATCH*NPIX*64;            // 128 f  (zero region start)
  float* statsP = statsE + 128;                         // 384 f
  float* colmax = statsP + 384;                         // 4096 f
  int*   done   = (int*)(colmax + 4096);                // 16 f (1 used)
  ushort* Qb    = (ushort*)(colmax + 4096 + 16);        // 9,764,864 hw each
  ushort* Kb    = Qb + (size_t)BATCH*4*NPIX*64;
  ushort* Vb    = Kb + (size_t)BATCH*4*NPIX*64;         // (unused)
  ushort* Ew    = Vb + (size_t)BATCH*4*NPIX*64;         // 9,764,864 hw
  ushort* w1T   = Ew + (size_t)BATCH*NPIX*256;          // 16,384 hw
  ushort* alinP = w1T + 16384;                          // 389,120 hw
  ushort* WqkP  = alinP + 389120;                       // 81,920 hw
  ushort* VP    = WqkP + 81920;                         // 9,961,472 hw
  ushort* projP = VP + 9961472;                         // 49,152 hw
  ushort* featsH = (ushort*)feats;
  ushort* featsL = (ushort*)F;

  // one launch: conv + weight-prep + zero(statsE..done = 4624 f32)
  k_front<<<775, 256, 0, stream>>>(x, conv1_w, conv1_b, conv2_w, conv2_b,
                                   alin_w, qlin_w, klin_w, lin1_w,
                                   kp_w, qp_w, vp_w,
                                   featsH, featsL, alinP, WqkP, w1T, projP,
                                   statsE);

  dim3 gp(5, BATCH, 3);
  k_proj_p1<<<gp, 256, 0, stream>>>(featsH, featsL, projP, kp_b, qp_b, vp_b, statsP);
  k_proj_p2<<<gp, 256, 0, stream>>>(featsH, featsL, projP, kp_b, qp_b, vp_b,
                                    knorm_g, knorm_b, qnorm_g, qnorm_b, vnorm_g, vnorm_b,
                                    statsP, Kb, Qb, VP);

  static bool attr_set = false;
  if (!attr_set){
    hipFuncSetAttribute((const void*)k_attn, hipFuncAttributeMaxDynamicSharedMemorySize, 162304);
    attr_set = true;
  }

  dim3 ga(5, BATCH*4);
  k_attn<<<ga, 512, 162304, stream>>>(Qb, Kb, alinP, WqkP, VP,
                                      qlin_b, klin_b, alin_b, Ew);

  dim3 gl(10, BATCH);
  k_lin1<<<gl, 256, 0, stream>>>(Ew, w1T, lin1_b, colmax, statsE, done,
                                 lin2_w, lin2_b, (float*)d_out);
}

// Round 20
// 491.449 us; speedup vs baseline: 1.0521x; 1.0521x over previous
//
#include <hip/hip_runtime.h>
#include <hip/hip_bf16.h>
#include <math.h>

typedef __hip_bfloat16 bf16;
typedef unsigned short ushort;
typedef __attribute__((ext_vector_type(8))) short short8;
typedef __attribute__((ext_vector_type(4))) float float4v;

#define BATCH 64
#define NPIX 596
#define CH 34
#define PC 256

static __device__ __forceinline__ ushort f2bu(float v){ bf16 h = __float2bfloat16(v); return *(ushort*)&h; }
static __device__ __forceinline__ float bu2f(ushort u){ bf16 h = *(bf16*)&u; return __bfloat162float(h); }
static __device__ __forceinline__ float eluf(float x){ return x > 0.f ? x : expm1f(x); }

// ---------------------------------------------------------------------------
// K_front: fusion of conv(512 blocks) + weight-prep(262 blocks) + zeroing.
// (R17 exact: scalar conv stores kept -- R19 showed LDS-staging them costs
// occupancy on this latency-bound path.)
// ---------------------------------------------------------------------------
__global__ __launch_bounds__(256) void k_front(
    const float* __restrict__ x,
    const float* __restrict__ w1, const float* __restrict__ b1,
    const float* __restrict__ w2, const float* __restrict__ b2,
    const float* __restrict__ aw, const float* __restrict__ qw, const float* __restrict__ kw,
    const float* __restrict__ l1w,
    const float* __restrict__ kpw, const float* __restrict__ qpw, const float* __restrict__ vpw,
    ushort* __restrict__ featsH, ushort* __restrict__ featsL,
    ushort* __restrict__ alinP, ushort* __restrict__ WqkP, ushort* __restrict__ w1T,
    ushort* __restrict__ projP,
    float* __restrict__ zbuf)
{
  __shared__ float shm_[3952];
  const int t = threadIdx.x;
  const int id = blockIdx.x;

  if (id < 512){
    float* sw1 = shm_;          // 256
    float* sb1 = shm_ + 256;    // 16
    float* sw2 = shm_ + 272;    // 2048
    float* sb2 = shm_ + 2320;   // 32
    float* h1  = shm_ + 2352;   // 1600
    const int s = id & 7, b = id >> 3;
    const float* xb = x + (size_t)b * 4*151*6;

    const int p0 = s*75;
    const int p1 = (p0+75 < NPIX) ? p0+75 : NPIX;
    const int rA = p0>>2, rB = (p1-1)>>2;
    const int nh = rB - rA + 2;

    sw1[t]=w1[t];
    if (t<16) sb1[t]=b1[t];
    for (int i=t;i<2048;i+=256) sw2[i]=w2[i];
    if (t<32) sb2[t]=b2[t];
    __syncthreads();

    for (int i=t; i<16*nh*5; i+=256){
      int oc = i/(nh*5), rem = i - oc*(nh*5);
      int lr = rem/5, cc = rem - (rem/5)*5;
      int r = rA + lr;
      float acc = sb1[oc];
      #pragma unroll
      for (int ic=0;ic<4;ic++){
        const float* xp = xb + ic*906 + r*6 + cc;
        const float* wp = sw1 + oc*16 + ic*4;
        acc += xp[0]*wp[0] + xp[1]*wp[1] + xp[6]*wp[2] + xp[7]*wp[3];
      }
      h1[(oc*20 + lr)*5 + cc] = fmaxf(acc, 0.f);
    }
    __syncthreads();

    const int np = p1 - p0;
    ushort* fbH = featsH + (size_t)b*NPIX*64;
    ushort* fbL = featsL + (size_t)b*NPIX*64;
    const short8 z8 = {0,0,0,0,0,0,0,0};
    for (int i=t;i<np*4;i+=256){
      int pl = i>>2, off = 32 + (i&3)*8;
      int p = p0 + pl;
      *(short8*)(fbH + (size_t)p*64 + off) = z8;
      *(short8*)(fbL + (size_t)p*64 + off) = z8;
    }
    for (int i=t;i<32*np;i+=256){
      int oc = i/np, pl = i - oc*np;
      int p = p0 + pl;
      int r = p>>2, cc = p&3;
      int lr = r - rA;
      float acc = sb2[oc];
      #pragma unroll
      for (int ic=0;ic<16;ic++){
        const float* hp = h1 + (ic*20 + lr)*5 + cc;
        const float* wp = sw2 + oc*64 + ic*4;
        acc += hp[0]*wp[0] + hp[1]*wp[1] + hp[5]*wp[2] + hp[6]*wp[3];
      }
      float v = fmaxf(acc, 0.f);
      ushort hu = f2bu(v);
      fbH[(size_t)p*64+oc] = hu;
      fbL[(size_t)p*64+oc] = f2bu(v - bu2f(hu));
    }
    __syncthreads();
    for (int pl=t; pl<np; pl+=256){
      int p = p0 + pl;
      float v1 = (float)(p&3)*0.25f;
      float v2 = (float)(p>>2)*(1.0f/149.0f);
      ushort h1u = f2bu(v1), h2u = f2bu(v2);
      fbH[(size_t)p*64+32] = h1u;  fbL[(size_t)p*64+32] = f2bu(v1 - bu2f(h1u));
      fbH[(size_t)p*64+33] = h2u;  fbL[(size_t)p*64+33] = f2bu(v2 - bu2f(h2u));
    }
  } else if (id < 774){
    const int w = t>>6, l = t&63;
    const int gw = (id - 512)*4 + w;
    #define SA(W_,R_,C_) shm_[(W_)*544 + (R_)*17 + (C_)]
    if (gw < 1016){
      const float* src; ushort* dst;
      int row0, col0, nrow, ncol, rstride; size_t slot;
      if (gw < 760){
        int tile = gw/19, kk = gw - tile*19;
        src = aw; rstride = NPIX; nrow = NPIX; ncol = NPIX;
        row0 = kk*32; col0 = tile*16;
        dst = alinP; slot = (size_t)gw*64;
      } else if (gw < 920){
        int g1 = gw - 760;
        int tile = g1>>2, kk = g1&3;
        rstride = NPIX; nrow = 64; ncol = NPIX;
        col0 = tile*16;
        if (kk < 2){ src = qw; row0 = kk*32; }
        else       { src = kw; row0 = (kk-2)*32; }
        dst = WqkP; slot = (size_t)g1*64;
      } else {
        int g2 = gw - 920;
        int which = g2>>5, rem = g2&31;
        int tile = rem>>1, kk = rem&1;
        src = which==0 ? kpw : which==1 ? qpw : vpw;
        rstride = PC; nrow = CH; ncol = PC;
        row0 = kk*32; col0 = tile*16;
        dst = projP; slot = (size_t)g2*64;
      }
      #pragma unroll
      for (int p=0;p<2;p++){
        int rr = p*16 + (l>>2);
        int r = row0 + rr;
        int cb = (l&3)*4;
        #pragma unroll
        for (int j=0;j<4;j++){
          int c = col0 + cb + j;
          float v = (r < nrow && c < ncol) ? src[(size_t)r*rstride + c] : 0.f;
          SA(w, rr, cb+j) = v;
        }
      }
      __syncthreads();
      int nloc = l&15, c0 = (l>>4)*8;
      ushort out[8];
      #pragma unroll
      for (int i=0;i<8;i++) out[i] = f2bu(SA(w, c0+i, nloc));
      *(short8*)(dst + (slot + l)*8) = *(short8*)out;
    } else {
      int s3 = (gw - 1016)*64 + l;      // 0..2047
      int n = s3>>5, e0 = (s3&31)*8;
      ushort out[8];
      #pragma unroll
      for (int i=0;i<8;i++) out[i] = f2bu(l1w[(size_t)(e0+i)*64 + n]);
      *(short8*)(w1T + (size_t)s3*8) = *(short8*)out;
    }
    #undef SA
  } else {
    for (int i=t;i<4624;i+=256) zbuf[i] = 0.f;
  }
}

// ---------------------------------------------------------------------------
// P1 (MFMA): proj stats. grid (10 rb, 64 b, 3 which).  (R17 exact)
// ---------------------------------------------------------------------------
__global__ __launch_bounds__(256) void k_proj_p1(
    const ushort* __restrict__ featsH, const ushort* __restrict__ featsL,
    const ushort* __restrict__ projP,
    const float* __restrict__ kpb, const float* __restrict__ qpb, const float* __restrict__ vpb,
    float* __restrict__ statsP)
{
  __shared__ float red[8];
  const int rb = blockIdx.x, b = blockIdx.y, which = blockIdx.z;
  const int t = threadIdx.x, w = t>>6, l = t&63, quad = l>>4, ln = l&15;
  const float* Bv = which==0 ? kpb : which==1 ? qpb : vpb;

  float4v acc[4][4];
  #pragma unroll
  for (int ms=0;ms<4;ms++)
    #pragma unroll
    for (int i=0;i<4;i++) acc[ms][i] = (float4v){0.f,0.f,0.f,0.f};

  #pragma unroll
  for (int kk=0;kk<4;kk++){
    const ushort* fb = (kk<2 ? featsH : featsL) + (size_t)b*NPIX*64;
    short8 aq[4];
    #pragma unroll
    for (int ms=0;ms<4;ms++){
      int r = rb*64 + ms*16 + ln;
      short8 z = {0,0,0,0,0,0,0,0};
      aq[ms] = (r < NPIX) ? *(const short8*)(fb + (size_t)r*64 + (kk&1)*32 + quad*8) : z;
    }
    #pragma unroll
    for (int i=0;i<4;i++){
      int tile = w + 4*i;
      short8 bf = *(const short8*)(projP + ((size_t)((which*16 + tile)*2 + (kk&1))*64 + l)*8);
      #pragma unroll
      for (int ms=0;ms<4;ms++)
        acc[ms][i] = __builtin_amdgcn_mfma_f32_16x16x32_bf16(aq[ms], bf, acc[ms][i], 0,0,0);
    }
  }
  float s=0.f, s2=0.f;
  #pragma unroll
  for (int i=0;i<4;i++){
    int col = (w+4*i)*16 + ln;
    float bc = Bv[col];
    #pragma unroll
    for (int ms=0;ms<4;ms++)
      #pragma unroll
      for (int r=0;r<4;r++){
        int p = rb*64 + ms*16 + quad*4 + r;
        if (p < NPIX){
          float v = acc[ms][i][r] + bc;
          s += v; s2 += v*v;
        }
      }
  }
  #pragma unroll
  for (int o=32;o>0;o>>=1){ s += __shfl_down(s,o); s2 += __shfl_down(s2,o); }
  if (l==0){ red[w]=s; red[4+w]=s2; }
  __syncthreads();
  if (t==0){
    atomicAdd(&statsP[(which*64+b)*2],   red[0]+red[1]+red[2]+red[3]);
    atomicAdd(&statsP[(which*64+b)*2+1], red[4]+red[5]+red[6]+red[7]);
  }
}

// ---------------------------------------------------------------------------
// P2 (MFMA): proj recompute + LN + affine; coalesced short8 emission via
// vtile LDS.  which 0/1 -> Kb/Qb rows; which==2 -> VP MFMA fragments.
// grid (10 rb, 64 b, 3 which).  (R17 exact)
// ---------------------------------------------------------------------------
__global__ __launch_bounds__(256) void k_proj_p2(
    const ushort* __restrict__ featsH, const ushort* __restrict__ featsL,
    const ushort* __restrict__ projP,
    const float* __restrict__ kpb, const float* __restrict__ qpb, const float* __restrict__ vpb,
    const float* __restrict__ kg, const float* __restrict__ kb_,
    const float* __restrict__ qg, const float* __restrict__ qb_,
    const float* __restrict__ vg, const float* __restrict__ vb_,
    const float* __restrict__ statsP,
    ushort* __restrict__ Kb, ushort* __restrict__ Qb, ushort* __restrict__ VP)
{
  __shared__ ushort vtile[64*264];
  const int rb = blockIdx.x, b = blockIdx.y, which = blockIdx.z;
  const int t = threadIdx.x, w = t>>6, l = t&63, quad = l>>4, ln = l&15;
  const float* Bv = which==0 ? kpb : which==1 ? qpb : vpb;
  const float* G  = which==0 ? kg  : which==1 ? qg  : vg;
  const float* Be = which==0 ? kb_ : which==1 ? qb_ : vb_;

  float4v acc[4][4];
  #pragma unroll
  for (int ms=0;ms<4;ms++)
    #pragma unroll
    for (int i=0;i<4;i++) acc[ms][i] = (float4v){0.f,0.f,0.f,0.f};

  #pragma unroll
  for (int kk=0;kk<4;kk++){
    const ushort* fb = (kk<2 ? featsH : featsL) + (size_t)b*NPIX*64;
    short8 aq[4];
    #pragma unroll
    for (int ms=0;ms<4;ms++){
      int r = rb*64 + ms*16 + ln;
      short8 z = {0,0,0,0,0,0,0,0};
      aq[ms] = (r < NPIX) ? *(const short8*)(fb + (size_t)r*64 + (kk&1)*32 + quad*8) : z;
    }
    #pragma unroll
    for (int i=0;i<4;i++){
      int tile = w + 4*i;
      short8 bf = *(const short8*)(projP + ((size_t)((which*16 + tile)*2 + (kk&1))*64 + l)*8);
      #pragma unroll
      for (int ms=0;ms<4;ms++)
        acc[ms][i] = __builtin_amdgcn_mfma_f32_16x16x32_bf16(aq[ms], bf, acc[ms][i], 0,0,0);
    }
  }
  const float n = (float)(NPIX*PC);
  const float S  = statsP[(which*64+b)*2];
  const float S2 = statsP[(which*64+b)*2+1];
  const float mu = S/n;
  const float rs = rsqrtf(S2/n - mu*mu + 1e-5f);

  // stage LN'd output into vtile [64 rows][264]
  #pragma unroll
  for (int i=0;i<4;i++){
    int col = (w+4*i)*16 + ln;
    int h = col>>6, d = col&63;
    float bc = Bv[col];
    #pragma unroll
    for (int ms=0;ms<4;ms++)
      #pragma unroll
      for (int r=0;r<4;r++){
        int lrow = ms*16 + quad*4 + r;
        int p = rb*64 + lrow;
        ushort o = 0;
        if (p < NPIX){
          int gi = (h*NPIX+p)*64 + d;
          o = f2bu((acc[ms][i][r] + bc - mu)*rs*G[gi] + Be[gi]);
        }
        vtile[lrow*264 + col] = o;
      }
  }
  __syncthreads();

  if (which < 2){
    // coalesced row emission: 64 rows x 32 short8 chunks = 2048 slots
    ushort* out = which==0 ? Kb : Qb;
    #pragma unroll
    for (int e=0;e<8;e++){
      int sid = e*256 + t;              // 0..2047
      int row = sid>>5, c8 = (sid&31)*8;
      int p = rb*64 + row;
      if (p < NPIX){
        int h = c8>>6, d0 = c8&63;
        *(short8*)(out + ((size_t)(b*4+h)*NPIX + p)*64 + d0) = *(short8*)(vtile + row*264 + c8);
      }
    }
  } else {
    // VP fragment emission
    #pragma unroll
    for (int e=0;e<8;e++){
      int sid = e*256 + t;              // 0..2047
      int l2 = sid & 63;
      int rest = sid >> 6;              // ((hh*4+w2)*2+kkL)
      int kkL = rest & 1, w2 = (rest>>1)&3, hh = rest>>3;
      int kk = rb*2 + kkL;
      if (kk < 19){
        int lrow0 = kkL*32 + ((l2>>4)<<3);
        int col = hh*64 + w2*16 + (l2&15);
        ushort o[8];
        #pragma unroll
        for (int jj=0;jj<8;jj++) o[jj] = vtile[(lrow0+jj)*264 + col];
        *(short8*)(VP + ((size_t)(b*4+hh)*4864 + (w2*19 + kk)*64 + l2)*8) = *(short8*)o;
      }
    }
  }
}

// ---------------------------------------------------------------------------
// K3: fused MFMA attention.  R9 geometry + 2-stage register double-buffer +
// LDS-staged coalesced Ew writes.  (R17 exact: 263us best)
// ---------------------------------------------------------------------------
__global__ __launch_bounds__(512, 1) void k_attn(
    const ushort* __restrict__ Qb, const ushort* __restrict__ Kb,
    const ushort* __restrict__ alinP, const ushort* __restrict__ WqkP,
    const ushort* __restrict__ VP,
    const float* __restrict__ qbias, const float* __restrict__ kbias,
    const float* __restrict__ abias,
    ushort* __restrict__ Ew)
{
  extern __shared__ __align__(16) ushort sm[];
  ushort* strip = sm;                         // 128*616 = 78,848 halves
  float*  red   = (float*)(sm + 78848);       // 1024 f32
  float*  rsum  = (float*)(sm + 78848 + 2048);// 128 f32

  const int t = threadIdx.x;
  const int w = t>>6, l = t&63, quad = l>>4, ln = l&15;
  const int id  = blockIdx.x + blockIdx.y*5;     // 0..1279
  const int xcd = id & 7, idx = id >> 3;         // idx 0..159
  const int lin = xcd*160 + idx;
  const int bh  = lin/5, rb = lin - bh*5;
  const int b = bh>>2, h = bh&3;
  const int row0 = rb*128;
  const ushort* Qp = Qb + (size_t)bh*NPIX*64;
  const ushort* Kp = Kb + (size_t)bh*NPIX*64;

  float4v acc[8][5];
  #pragma unroll
  for (int ms=0;ms<8;ms++)
    #pragma unroll
    for (int i=0;i<5;i++) acc[ms][i] = (float4v){0.f,0.f,0.f,0.f};

  // ---------------- A0 = elu([Q|K] @ Wqk + qb + kb) ----------------
  #pragma unroll
  for (int kk=0;kk<4;kk++){
    short8 aq[8];
    #pragma unroll
    for (int ms=0;ms<8;ms++){
      int r = row0 + ms*16 + ln;
      short8 z = {0,0,0,0,0,0,0,0};
      aq[ms] = (r < NPIX)
        ? *(const short8*)((kk<2 ? Qp : Kp) + (size_t)r*64 + (kk&1)*32 + quad*8) : z;
    }
    __builtin_amdgcn_s_setprio(1);
    #pragma unroll
    for (int i=0;i<5;i++){
      int tile = w + 8*i;
      short8 bf = *(const short8*)(WqkP + ((size_t)(tile*4 + kk)*64 + l)*8);
      #pragma unroll
      for (int ms=0;ms<8;ms++)
        acc[ms][i] = __builtin_amdgcn_mfma_f32_16x16x32_bf16(aq[ms], bf, acc[ms][i], 0,0,0);
    }
    __builtin_amdgcn_s_setprio(0);
  }
  // epilogue: bias + elu -> strip
  #pragma unroll
  for (int i=0;i<5;i++){
    int t0 = w + 8*i;
    if (t0 < 38){
      int col = t0*16 + ln;
      bool cv = col < NPIX;
      float qkb = cv ? (qbias[col] + kbias[col]) : 0.f;
      #pragma unroll
      for (int ms=0;ms<8;ms++)
        #pragma unroll
        for (int r=0;r<4;r++){
          float v = 0.f;
          if (cv){ float xx = acc[ms][i][r] + qkb; v = xx > 0.f ? xx : __expf(xx) - 1.f; }
          strip[(ms*16+quad*4+r)*616 + col] = f2bu(v);
        }
    }
  }
  __syncthreads();

  // ---------------- S = A0 @ alin (2-stage B prefetch) ----------------
  #pragma unroll
  for (int ms=0;ms<8;ms++)
    #pragma unroll
    for (int i=0;i<5;i++) acc[ms][i] = (float4v){0.f,0.f,0.f,0.f};

#define LDB(dst, KK) \
  { _Pragma("unroll") \
    for (int i=0;i<5;i++) \
      dst[i] = *(const short8*)(alinP + ((size_t)((w+8*i)*19 + (KK))*64 + l)*8); }
#define SCOMP(KK, bfv) \
  { short8 af[8]; \
    _Pragma("unroll") \
    for (int ms=0;ms<8;ms++) \
      af[ms] = *(const short8*)(strip + (ms*16+ln)*616 + (KK)*32 + quad*8); \
    __builtin_amdgcn_s_setprio(1); \
    _Pragma("unroll") \
    for (int i=0;i<5;i++){ \
      _Pragma("unroll") \
      for (int ms=0;ms<8;ms++) \
        acc[ms][i] = __builtin_amdgcn_mfma_f32_16x16x32_bf16(af[ms], bfv[i], acc[ms][i], 0,0,0); \
    } \
    __builtin_amdgcn_s_setprio(0); }

  {
    short8 bfA[5], bfB[5];
    LDB(bfA, 0);
    for (int kk=0; kk<18; kk+=2){
      LDB(bfB, kk+1);
      SCOMP(kk, bfA);
      LDB(bfA, kk+2);
      SCOMP(kk+1, bfB);
    }
    SCOMP(18, bfA);
  }
  __syncthreads();   // all strip (A0) reads done before P overwrites it

  // -------- fused exp + row-sum, unnormalized P -> strip (no max pass) -----
  float sum[8][4];
  #pragma unroll
  for (int ms=0;ms<8;ms++)
    #pragma unroll
    for (int r=0;r<4;r++) sum[ms][r] = 0.f;
  #pragma unroll
  for (int i=0;i<5;i++){
    int t0 = w + 8*i;
    if (t0 < 38){
      int col = t0*16 + ln;
      bool cv = col < NPIX;
      float ab = cv ? abias[col] : 0.f;
      #pragma unroll
      for (int ms=0;ms<8;ms++)
        #pragma unroll
        for (int r=0;r<4;r++){
          float e = cv ? __expf(acc[ms][i][r] + ab) : 0.f;
          sum[ms][r] += e;
          strip[(ms*16+quad*4+r)*616 + col] = f2bu(e);
        }
    }
  }
  #pragma unroll
  for (int ms=0;ms<8;ms++)
    #pragma unroll
    for (int r=0;r<4;r++)
      #pragma unroll
      for (int o=8;o>0;o>>=1) sum[ms][r] += __shfl_xor(sum[ms][r], o, 16);
  if (ln==0){
    #pragma unroll
    for (int ms=0;ms<8;ms++)
      #pragma unroll
      for (int r=0;r<4;r++) red[(ms*16+quad*4+r)*8 + w] = sum[ms][r];
  }
  __syncthreads();
  if (t < 128){
    float4v v0 = *(float4v*)&red[t*8];
    float4v v1 = *(float4v*)&red[t*8+4];
    rsum[t] = (v0[0]+v0[1]+v0[2]+v0[3]) + (v1[0]+v1[1]+v1[2]+v1[3]);
  }
  __syncthreads();

  // ---------------- E = (P_unnorm @ V) * inv_rowsum (2-stage prefetch) ----
  const int wr = w>>2, wc = w&3;
  float4v ve[4];
  #pragma unroll
  for (int ms=0;ms<4;ms++) ve[ms] = (float4v){0.f,0.f,0.f,0.f};

#define LDV(dst, KK) \
  dst = *(const short8*)(VP + ((size_t)bh*4864 + (wc*19 + (KK))*64 + l)*8);
#define PVCOMP(KK, bfv) \
  { __builtin_amdgcn_s_setprio(1); \
    _Pragma("unroll") \
    for (int ms=0;ms<4;ms++){ \
      short8 af = *(const short8*)(strip + (wr*64 + ms*16+ln)*616 + (KK)*32 + quad*8); \
      ve[ms] = __builtin_amdgcn_mfma_f32_16x16x32_bf16(af, bfv, ve[ms], 0,0,0); \
    } \
    __builtin_amdgcn_s_setprio(0); }

  {
    short8 vA, vB;
    LDV(vA, 0);
    for (int kk=0; kk<18; kk+=2){
      LDV(vB, kk+1);
      PVCOMP(kk, vA);
      LDV(vA, kk+2);
      PVCOMP(kk+1, vB);
    }
    PVCOMP(18, vA);
  }

  // stage E in dead strip, then coalesced short8 Ew writes
  __syncthreads();   // all strip (P) reads done
  {
    ushort* esh = sm;  // 128 rows x 64 cols, stride 72
    #pragma unroll
    for (int ms=0;ms<4;ms++)
      #pragma unroll
      for (int r=0;r<4;r++){
        int lrow = wr*64 + ms*16 + quad*4 + r;
        esh[lrow*72 + wc*16 + ln] = f2bu(ve[ms][r] / rsum[lrow]);
      }
    __syncthreads();
    #pragma unroll
    for (int e=0;e<2;e++){
      int sid = e*512 + t;          // 0..1023 = 128 rows x 8 chunks
      int row = sid>>3, c8 = (sid&7)*8;
      int p = row0 + row;
      if (p < NPIX)
        *(short8*)(Ew + ((size_t)b*NPIX + p)*256 + h*64 + c8) = *(short8*)(esh + row*72 + c8);
    }
  }
}

// ---------------------------------------------------------------------------
// K4: lin1 via MFMA + relu + per-batch LN stats + per-column max; last-block
// tail does final LN+lin2+elu (device-scope atomics + threadfence).
// ---------------------------------------------------------------------------
__global__ __launch_bounds__(256) void k_lin1(
    const ushort* __restrict__ Ew, const ushort* __restrict__ w1T,
    const float* __restrict__ bias,
    float* __restrict__ colmax, float* __restrict__ stats,
    int* __restrict__ done,
    const float* __restrict__ w2, const float* __restrict__ b2v,
    float* __restrict__ out)
{
  __shared__ ushort sw1[64*264];
  __shared__ float red[8];
  __shared__ int lastFlag;
  const int t = threadIdx.x;
  const int w = t>>6, l = t&63, quad = l>>4, ln = l&15;
  const int rb = blockIdx.x, b = blockIdx.y;
  for (int g=t; g<2048; g+=256){
    int row = g>>5, q = g&31;
    *(short8*)(sw1 + row*264 + q*8) = *(const short8*)(w1T + row*256 + q*8);
  }
  __syncthreads();
  float4v acc[4];
  #pragma unroll
  for (int ms=0;ms<4;ms++) acc[ms] = (float4v){0.f,0.f,0.f,0.f};
  #pragma unroll
  for (int kk=0;kk<8;kk++){
    short8 bf = *(const short8*)(sw1 + (w*16+ln)*264 + kk*32 + quad*8);
    #pragma unroll
    for (int ms=0;ms<4;ms++){
      int p = rb*64 + ms*16 + ln;
      size_t rowi = (size_t)b*NPIX + (p < NPIX ? p : 0);
      short8 a = *(const short8*)(Ew + rowi*256 + kk*32 + quad*8);
      acc[ms] = __builtin_amdgcn_mfma_f32_16x16x32_bf16(a, bf, acc[ms], 0,0,0);
    }
  }
  const int col = w*16 + ln;
  const float bc = bias[col];
  float s=0.f, s2=0.f, cmx=0.f;
  #pragma unroll
  for (int ms=0;ms<4;ms++)
    #pragma unroll
    for (int r=0;r<4;r++){
      int p = rb*64 + ms*16 + quad*4 + r;
      if (p < NPIX){
        float v = fmaxf(acc[ms][r] + bc, 0.f);
        s += v; s2 += v*v;
        cmx = fmaxf(cmx, v);
      }
    }
  cmx = fmaxf(cmx, __shfl_xor(cmx, 16, 64));
  cmx = fmaxf(cmx, __shfl_xor(cmx, 32, 64));
  if (quad == 0)
    atomicMax((int*)&colmax[b*64 + col], __float_as_int(cmx));
  #pragma unroll
  for (int o=32;o>0;o>>=1){ s += __shfl_down(s,o); s2 += __shfl_down(s2,o); }
  if (l==0){ red[w]=s; red[4+w]=s2; }
  __syncthreads();
  if (t==0){
    atomicAdd(&stats[b*2],   red[0]+red[1]+red[2]+red[3]);
    atomicAdd(&stats[b*2+1], red[4]+red[5]+red[6]+red[7]);
    __threadfence();
    int v = atomicAdd(done, 1);
    lastFlag = (v == 639);
  }
  __syncthreads();
  if (lastFlag && t < 64){
    const int bb = t;
    const float n = (float)(NPIX*64);
    float S = stats[bb*2], S2 = stats[bb*2+1];
    float mu = S/n, var = S2/n - mu*mu;
    float rs = rsqrtf(var + 1e-5f);
    float accv[10];
    #pragma unroll
    for (int j=0;j<10;j++) accv[j] = b2v[j];
    for (int e=0;e<64;e++){
      float nm = (colmax[bb*64+e] - mu) * rs;
      #pragma unroll
      for (int j=0;j<10;j++) accv[j] += nm * w2[e*10+j];
    }
    #pragma unroll
    for (int j=0;j<10;j++) out[bb*10+j] = eluf(accv[j]);
  }
}

// ---------------------------------------------------------------------------
extern "C" void kernel_launch(void* const* d_in, const int* in_sizes, int n_in,
                              void* d_out, int out_size, void* d_ws, size_t ws_size,
                              hipStream_t stream)
{
  const float* x       = (const float*)d_in[0];
  const float* conv1_w = (const float*)d_in[1];
  const float* conv1_b = (const float*)d_in[2];
  const float* conv2_w = (const float*)d_in[3];
  const float* conv2_b = (const float*)d_in[4];
  const float* kp_w    = (const float*)d_in[5];
  const float* kp_b    = (const float*)d_in[6];
  const float* qp_w    = (const float*)d_in[7];
  const float* qp_b    = (const float*)d_in[8];
  const float* vp_w    = (const float*)d_in[9];
  const float* vp_b    = (const float*)d_in[10];
  const float* klin_w  = (const float*)d_in[11];
  const float* klin_b  = (const float*)d_in[12];
  const float* qlin_w  = (const float*)d_in[13];
  const float* qlin_b  = (const float*)d_in[14];
  const float* alin_w  = (const float*)d_in[15];
  const float* alin_b  = (const float*)d_in[16];
  const float* knorm_g = (const float*)d_in[17];
  const float* knorm_b = (const float*)d_in[18];
  const float* qnorm_g = (const float*)d_in[19];
  const float* qnorm_b = (const float*)d_in[20];
  const float* vnorm_g = (const float*)d_in[21];
  const float* vnorm_b = (const float*)d_in[22];
  const float* lin1_w  = (const float*)d_in[23];
  const float* lin1_b  = (const float*)d_in[24];
  const float* lin2_w  = (const float*)d_in[25];
  const float* lin2_b  = (const float*)d_in[26];

  // workspace layout
  float* feats  = (float*)d_ws;                         // holds featsH bf16
  float* F      = feats + (size_t)BATCH*NPIX*CH;        // holds featsL bf16
  float* statsE = F + (size_t)BATCH*NPIX*64;            // 128 f  (zero region start)
  float* statsP = statsE + 128;                         // 384 f
  float* colmax = statsP + 384;                         // 4096 f
  int*   done   = (int*)(colmax + 4096);                // 16 f (1 used)
  ushort* Qb    = (ushort*)(colmax + 4096 + 16);        // 9,764,864 hw each
  ushort* Kb    = Qb + (size_t)BATCH*4*NPIX*64;
  ushort* Vb    = Kb + (size_t)BATCH*4*NPIX*64;         // (unused)
  ushort* Ew    = Vb + (size_t)BATCH*4*NPIX*64;         // 9,764,864 hw
  ushort* w1T   = Ew + (size_t)BATCH*NPIX*256;          // 16,384 hw
  ushort* alinP = w1T + 16384;                          // 389,120 hw
  ushort* WqkP  = alinP + 389120;                       // 81,920 hw
  ushort* VP    = WqkP + 81920;                         // 9,961,472 hw
  ushort* projP = VP + 9961472;                         // 49,152 hw
  ushort* featsH = (ushort*)feats;
  ushort* featsL = (ushort*)F;

  // one launch: conv + weight-prep + zero(statsE..done = 4624 f32)
  k_front<<<775, 256, 0, stream>>>(x, conv1_w, conv1_b, conv2_w, conv2_b,
                                   alin_w, qlin_w, klin_w, lin1_w,
                                   kp_w, qp_w, vp_w,
                                   featsH, featsL, alinP, WqkP, w1T, projP,
                                   statsE);

  dim3 gp(10, BATCH, 3);
  k_proj_p1<<<gp, 256, 0, stream>>>(featsH, featsL, projP, kp_b, qp_b, vp_b, statsP);
  k_proj_p2<<<gp, 256, 0, stream>>>(featsH, featsL, projP, kp_b, qp_b, vp_b,
                                    knorm_g, knorm_b, qnorm_g, qnorm_b, vnorm_g, vnorm_b,
                                    statsP, Kb, Qb, VP);

  static bool attr_set = false;
  if (!attr_set){
    hipFuncSetAttribute((const void*)k_attn, hipFuncAttributeMaxDynamicSharedMemorySize, 162304);
    attr_set = true;
  }

  dim3 ga(5, BATCH*4);
  k_attn<<<ga, 512, 162304, stream>>>(Qb, Kb, alinP, WqkP, VP,
                                      qlin_b, klin_b, alin_b, Ew);

  dim3 gl(10, BATCH);
  k_lin1<<<gl, 256, 0, stream>>>(Ew, w1T, lin1_b, colmax, statsE, done,
                                 lin2_w, lin2_b, (float*)d_out);
}